// Round 12
// baseline (67.881 us; speedup 1.0000x reference)
//
#include <hip/hip_runtime.h>

#define M_TOT 32768
#define K_TOT 768
#define N_TOT 768

typedef int v4i __attribute__((ext_vector_type(4)));
typedef unsigned int v4u __attribute__((ext_vector_type(4)));

#define GLOAD_LDS(g, l) __builtin_amdgcn_global_load_lds( \
    (const __attribute__((address_space(1))) unsigned int*)(g), \
    (__attribute__((address_space(3))) unsigned int*)(l), 16, 0, 0)

// Pack 4 int32 (each holding an int8 value) into one dword of 4 bytes. (verified R2)
__device__ __forceinline__ unsigned pack4(v4i a) {
  unsigned lo = __builtin_amdgcn_perm((unsigned)a.y, (unsigned)a.x, 0x00000400u);
  unsigned hi = __builtin_amdgcn_perm((unsigned)a.w, (unsigned)a.z, 0x00000400u);
  return __builtin_amdgcn_perm(hi, lo, 0x05040100u);
}

// W[k][n] int32 -> W8T[n][k] int8 (transposed, packed)
__global__ __launch_bounds__(256) void pack_w_kernel(const int* __restrict__ W,
                                                     signed char* __restrict__ W8T) {
  __shared__ signed char t[64][72];
  const int k0 = blockIdx.x * 64, n0 = blockIdx.y * 64;
  for (int i = threadIdx.x; i < 4096; i += 256) {
    int k = i >> 6, n = i & 63;
    t[n][k] = (signed char)W[(k0 + k) * N_TOT + n0 + n];
  }
  __syncthreads();
  for (int i = threadIdx.x; i < 4096; i += 256) {
    int n = i >> 6, k = i & 63;
    W8T[(n0 + n) * K_TOT + k0 + k] = t[n][k];
  }
}

// X int32 [25165824] -> X8 int8 (same order). Fully coalesced both sides:
// per j-slice, consecutive threads read consecutive 16B and write consecutive
// 4B. 524288 threads x 12 chunks covers 6291456 4-int32 chunks exactly.
__global__ __launch_bounds__(256) void pack_x_kernel(const int* __restrict__ X,
                                                     unsigned* __restrict__ X8) {
  const int gtid = blockIdx.x * 256 + threadIdx.x;  // 0..524287
  const int NT = 2048 * 256;
#pragma unroll
  for (int b = 0; b < 3; ++b) {
    v4i v[4];
#pragma unroll
    for (int j = 0; j < 4; ++j)
      v[j] = *(const v4i*)(X + (size_t)((b * 4 + j) * NT + gtid) * 4);
#pragma unroll
    for (int j = 0; j < 4; ++j)
      X8[(b * 4 + j) * NT + gtid] = pack4(v[j]);
  }
}

// Pass-2 GEMM: out_i32 = clamp(round((X8@W)*alpha + bias))
// R4's proven tile (BM=BN=128, BK=64, 4 waves 2x2, wave 64x64, 4x4 mfma)
// with the A-path converted to pure global_load_lds from packed X8:
// no q regs, no pack4, no ds_writes, no mid-wait. Stage = 2 A + 2 B
// gload_lds = 4 vmem ops; ring-3 both; issue k+2 at top of iter k.
// FIFO ledger: entering top of iter k outstanding [S(k)4, S(k+1)4];
// TOP vmcnt(4) drains S(k); last iter vmcnt(0). ONE wait + ONE barrier/iter.
__global__ __launch_bounds__(256, 3) void gemm_i8_p2(
    const signed char* __restrict__ X8, const signed char* __restrict__ W8T,
    const float* __restrict__ bias, const float* __restrict__ alpha_p,
    int* __restrict__ out) {
  __shared__ __align__(16) signed char Albuf[3][8192];
  __shared__ __align__(16) signed char Blbuf[3][8192];

  // Bijective XCD-chunked swizzle: 1536 wgs = 8 XCDs x 192; nt fast so the 6
  // sibling N-tiles of one X8 M-panel share that XCD's L2.
  const int d = blockIdx.x;
  const int t = (d & 7) * 192 + (d >> 3);
  const int mt = t / 6, nt = t - mt * 6;
  const int row0 = mt << 7, col0 = nt << 7;

  const int tid = threadIdx.x;
  const int lane = tid & 63;
  const int wave = tid >> 6;
  const int wr = wave >> 1, wc = wave & 1;
  const int fr = lane & 15, fg = lane >> 4;
  const int fsw = (fr & 3) << 4;          // frag-read XOR swizzle

  // Staging chunks c = i*256+tid: row r = c>>2 (0..127), 16B slot c&3.
  // Source pre-swizzled so linear LDS dest + swizzled frag read agree
  // (rule #21 involution: slot ^= (r&3)).
  int asrc[2], bsrc[2], sdst[2];
#pragma unroll
  for (int i = 0; i < 2; ++i) {
    int c = i * 256 + tid;
    int r = c >> 2, s = (c & 3) << 4;
    int sw = s ^ ((r & 3) << 4);
    asrc[i] = (row0 + r) * K_TOT + sw;
    bsrc[i] = (col0 + r) * K_TOT + sw;
    sdst[i] = i * 4096 + wave * 1024;     // wave-uniform base; HW adds lane*16
  }

  const v4i zero = {0, 0, 0, 0};
  v4i acc[4][4];
#pragma unroll
  for (int m = 0; m < 4; ++m)
#pragma unroll
    for (int n = 0; n < 4; ++n) acc[m][n] = zero;

#define P2_ISSUE(ks)                                                     \
  do {                                                                   \
    const signed char* _xa = X8 + (ks) * 64;                             \
    const signed char* _wb = W8T + (ks) * 64;                            \
    signed char* _la = Albuf[(ks) % 3];                                  \
    signed char* _lb = Blbuf[(ks) % 3];                                  \
    GLOAD_LDS(_xa + asrc[0], _la + sdst[0]);                             \
    GLOAD_LDS(_xa + asrc[1], _la + sdst[1]);                             \
    GLOAD_LDS(_wb + bsrc[0], _lb + sdst[0]);                             \
    GLOAD_LDS(_wb + bsrc[1], _lb + sdst[1]);                             \
  } while (0)

#define P2_MFMA(ks)                                                      \
  do {                                                                   \
    v4i af[4], bf[4];                                                    \
    const signed char* _ab = Albuf[(ks) % 3];                            \
    const signed char* _bb = Blbuf[(ks) % 3];                            \
    const int _kb = (fg << 4) ^ fsw;                                     \
    _Pragma("unroll") for (int m = 0; m < 4; ++m)                        \
        af[m] = *(const v4i*)&_ab[(wr * 64 + m * 16 + fr) * 64 + _kb];   \
    _Pragma("unroll") for (int n = 0; n < 4; ++n)                        \
        bf[n] = *(const v4i*)&_bb[(wc * 64 + n * 16 + fr) * 64 + _kb];   \
    __builtin_amdgcn_s_setprio(1);                                       \
    _Pragma("unroll") for (int m = 0; m < 4; ++m)                        \
        _Pragma("unroll") for (int n = 0; n < 4; ++n)                    \
            acc[m][n] = __builtin_amdgcn_mfma_i32_16x16x64_i8(           \
                af[m], bf[n], acc[m][n], 0, 0, 0);                       \
    __builtin_amdgcn_s_setprio(0);                                       \
  } while (0)

  // Safety: issuing S(ks+2) overwrites ring slot (ks-1)%3; all waves passed
  // this iter's barrier only after their iter-(ks-1) ds_reads retired
  // (compiler lgkm waits precede each consuming MFMA).
#define P2_ITER(ks, TOPW, DOI)                                           \
  do {                                                                   \
    asm volatile("s_waitcnt vmcnt(" TOPW ")" ::: "memory");              \
    __builtin_amdgcn_s_barrier();                                        \
    if (DOI) P2_ISSUE((ks) + 2);                                         \
    P2_MFMA(ks);                                                         \
  } while (0)

  P2_ISSUE(0);
  P2_ISSUE(1);

  P2_ITER(0, "4", 1);
  P2_ITER(1, "4", 1);
  P2_ITER(2, "4", 1);
  P2_ITER(3, "4", 1);
  P2_ITER(4, "4", 1);
  P2_ITER(5, "4", 1);
  P2_ITER(6, "4", 1);
  P2_ITER(7, "4", 1);
  P2_ITER(8, "4", 1);
  P2_ITER(9, "4", 1);   // issues stage 11 (last)
  P2_ITER(10, "4", 0);  // outstanding S10,S11 -> drain S10
  P2_ITER(11, "0", 0);

  // Epilogue: C/D layout col = lane&15, row = (lane>>4)*4 + reg. Output int32.
  const float alpha = *alpha_p;
  float bv[4];
#pragma unroll
  for (int n = 0; n < 4; ++n) bv[n] = bias[col0 + wc * 64 + n * 16 + fr];

#pragma unroll
  for (int m = 0; m < 4; ++m) {
    int orow = row0 + wr * 64 + m * 16 + fg * 4;
#pragma unroll
    for (int n = 0; n < 4; ++n) {
      int ocol = col0 + wc * 64 + n * 16 + fr;
      int* po = out + orow * N_TOT + ocol;
#pragma unroll
      for (int r = 0; r < 4; ++r) {
        float v = rintf((float)acc[m][n][r] * alpha + bv[n]);
        v = fminf(127.f, fmaxf(-128.f, v));
        po[r * N_TOT] = (int)v;
      }
    }
  }
}

// ---------------- Fallback: R4 kernel verbatim (55us proven) ----------------
__global__ __launch_bounds__(256, 2) void gemm_i8_fb(
    const int* __restrict__ X, const signed char* __restrict__ W8T,
    const float* __restrict__ bias, const float* __restrict__ alpha_p,
    int* __restrict__ out) {
  __shared__ __align__(16) signed char Abuf[2][8192];
  __shared__ __align__(16) signed char Bbuf[3][8192];
  const int d = blockIdx.x;
  const int t = (d & 7) * 192 + (d >> 3);
  const int mt = t / 6, nt = t - mt * 6;
  const int row0 = mt << 7, col0 = nt << 7;
  const int tid = threadIdx.x;
  const int lane = tid & 63;
  const int wave = tid >> 6;
  const int wr = wave >> 1, wc = wave & 1;
  const int fr = lane & 15, fg = lane >> 4;
  const int fsw = (fr & 3) << 4;
  const int arow = tid >> 4;
  const int acol = (tid & 15) << 2;
  const int* Xbase = X + (row0 + arow) * K_TOT + acol;
  const int awsw = (arow & 3) << 4;
  int bsrc[2], bdst[2];
#pragma unroll
  for (int i = 0; i < 2; ++i) {
    int c = i * 256 + tid;
    int r = c >> 2, s = (c & 3) << 4;
    bsrc[i] = (col0 + r) * K_TOT + (s ^ ((r & 3) << 4));
    bdst[i] = i * 4096 + wave * 1024;
  }
  v4i q[2][8];
  const v4i zero = {0, 0, 0, 0};
  v4i acc[4][4];
#pragma unroll
  for (int m = 0; m < 4; ++m)
#pragma unroll
    for (int n = 0; n < 4; ++n) acc[m][n] = zero;
#define FB_ISSUE_A(ks)                                                   \
  do {                                                                   \
    const int* _p = Xbase + (ks) * 64;                                   \
    _Pragma("unroll") for (int j = 0; j < 8; ++j)                        \
        q[(ks) & 1][j] = *(const v4i*)(_p + j * 16 * K_TOT);             \
  } while (0)
#define FB_ISSUE_B(ks)                                                   \
  do {                                                                   \
    const signed char* _w = W8T + (ks) * 64;                             \
    signed char* _lb = Bbuf[(ks) % 3];                                   \
    GLOAD_LDS(_w + bsrc[0], _lb + bdst[0]);                              \
    GLOAD_LDS(_w + bsrc[1], _lb + bdst[1]);                              \
  } while (0)
#define FB_PACK_A(tt)                                                    \
  do {                                                                   \
    signed char* _ab = Abuf[(tt) & 1];                                   \
    _Pragma("unroll") for (int j = 0; j < 8; ++j) {                      \
      unsigned _dw = pack4(q[(tt) & 1][j]);                              \
      *(unsigned*)&_ab[(16 * j + arow) * 64 + (acol ^ awsw)] = _dw;      \
    }                                                                    \
  } while (0)
#define FB_MFMA(ks)                                                      \
  do {                                                                   \
    v4i af[4], bf[4];                                                    \
    const signed char* _ab = Abuf[(ks) & 1];                             \
    const signed char* _bb = Bbuf[(ks) % 3];                             \
    const int _kb = (fg << 4) ^ fsw;                                     \
    _Pragma("unroll") for (int m = 0; m < 4; ++m)                        \
        af[m] = *(const v4i*)&_ab[(wr * 64 + m * 16 + fr) * 64 + _kb];   \
    _Pragma("unroll") for (int n = 0; n < 4; ++n)                        \
        bf[n] = *(const v4i*)&_bb[(wc * 64 + n * 16 + fr) * 64 + _kb];   \
    __builtin_amdgcn_s_setprio(1);                                       \
    _Pragma("unroll") for (int m = 0; m < 4; ++m)                        \
        _Pragma("unroll") for (int n = 0; n < 4; ++n)                    \
            acc[m][n] = __builtin_amdgcn_mfma_i32_16x16x64_i8(           \
                af[m], bf[n], acc[m][n], 0, 0, 0);                       \
    __builtin_amdgcn_s_setprio(0);                                       \
  } while (0)
#define FB_ITER(ks, TOPW, MIDW)                                          \
  do {                                                                   \
    asm volatile("s_waitcnt vmcnt(" TOPW ") lgkmcnt(0)" ::: "memory");   \
    __builtin_amdgcn_s_barrier();                                        \
    if ((ks) + 2 < 12) { FB_ISSUE_A((ks) + 2); FB_ISSUE_B((ks) + 2); }   \
    FB_MFMA(ks);                                                         \
    if ((ks) + 1 < 12) {                                                 \
      asm volatile("s_waitcnt vmcnt(" MIDW ")" ::: "memory");            \
      FB_PACK_A((ks) + 1);                                               \
    }                                                                    \
  } while (0)
  FB_ISSUE_A(0); FB_ISSUE_B(0);
  FB_ISSUE_A(1); FB_ISSUE_B(1);
  asm volatile("s_waitcnt vmcnt(12)" ::: "memory");
  FB_PACK_A(0);
  FB_ITER(0, "10", "12");
  FB_ITER(1, "10", "12");
  FB_ITER(2, "10", "12");
  FB_ITER(3, "10", "12");
  FB_ITER(4, "10", "12");
  FB_ITER(5, "10", "12");
  FB_ITER(6, "10", "12");
  FB_ITER(7, "10", "12");
  FB_ITER(8, "10", "12");
  FB_ITER(9, "10", "12");
  FB_ITER(10, "10", "2");
  FB_ITER(11, "0", "0");
  const float alpha = *alpha_p;
  float bv[4];
#pragma unroll
  for (int n = 0; n < 4; ++n) bv[n] = bias[col0 + wc * 64 + n * 16 + fr];
#pragma unroll
  for (int m = 0; m < 4; ++m) {
    int orow = row0 + wr * 64 + m * 16 + fg * 4;
#pragma unroll
    for (int n = 0; n < 4; ++n) {
      int ocol = col0 + wc * 64 + n * 16 + fr;
      int* po = out + orow * N_TOT + ocol;
#pragma unroll
      for (int r = 0; r < 4; ++r) {
        float v = rintf((float)acc[m][n][r] * alpha + bv[n]);
        v = fminf(127.f, fmaxf(-128.f, v));
        po[r * N_TOT] = (int)v;
      }
    }
  }
}

extern "C" void kernel_launch(void* const* d_in, const int* in_sizes, int n_in,
                              void* d_out, int out_size, void* d_ws, size_t ws_size,
                              hipStream_t stream) {
  const int* X = (const int*)d_in[0];        // [4,8192,768] int8 promoted to int32
  const int* W = (const int*)d_in[1];        // [768,768] int8 promoted to int32
  const float* bias = (const float*)d_in[2]; // [1,768] fp16 promoted to float32
  const float* alpha = (const float*)d_in[3];
  int* out = (int*)d_out;

  signed char* W8T = (signed char*)d_ws;                 // 589,824 B at offset 0
  signed char* X8 = (signed char*)d_ws + (1 << 20);      // 25,165,824 B at 1MB

  dim3 pg(K_TOT / 64, N_TOT / 64);
  pack_w_kernel<<<pg, 256, 0, stream>>>(W, W8T);

  if (ws_size >= (size_t)(1 << 20) + (size_t)M_TOT * K_TOT) {
    pack_x_kernel<<<2048, 256, 0, stream>>>(X, (unsigned*)X8);
    gemm_i8_p2<<<(M_TOT / 128) * (N_TOT / 128), 256, 0, stream>>>(
        X8, W8T, bias, alpha, out);
  } else {
    gemm_i8_fb<<<(M_TOT / 128) * (N_TOT / 128), 256, 0, stream>>>(
        X, W8T, bias, alpha, out);
  }
}